// Round 12
// baseline (2474.824 us; speedup 1.0000x reference)
//
#include <hip/hip_runtime.h>
#include <hip/hip_bf16.h>

#define F 128
#define NBUCK 8

typedef float floatx2 __attribute__((ext_vector_type(2)));
typedef float f32x4 __attribute__((ext_vector_type(4)));
typedef short short8 __attribute__((ext_vector_type(8)));

static __device__ __forceinline__ unsigned short f2bf(float f) {
    unsigned int u = __float_as_uint(f);
    unsigned int r = (u + 0x7fffu + ((u >> 16) & 1u)) >> 16;   // RTN-even
    return (unsigned short)r;
}

static __device__ __forceinline__ float4 fp8x4_to_f32(unsigned int w) {
    floatx2 lo = __builtin_amdgcn_cvt_pk_f32_fp8((int)w, false);
    floatx2 hi = __builtin_amdgcn_cvt_pk_f32_fp8((int)w, true);
    return make_float4(lo[0], lo[1], hi[0], hi[1]);
}

static __device__ __forceinline__ unsigned int f32x4_to_fp8(float a, float b, float c, float d) {
    int w = 0;
    w = __builtin_amdgcn_cvt_pk_fp8_f32(a, b, w, false);
    w = __builtin_amdgcn_cvt_pk_fp8_f32(c, d, w, true);
    return (unsigned int)w;
}

// decode 16 fp8 (uint4) and masked-accumulate into a[16]
static __device__ __forceinline__ void acc16(float* a, uint4 w, float m) {
    float4 t;
    t = fp8x4_to_f32(w.x);
    a[0]  = fmaf(m, t.x, a[0]);  a[1]  = fmaf(m, t.y, a[1]);
    a[2]  = fmaf(m, t.z, a[2]);  a[3]  = fmaf(m, t.w, a[3]);
    t = fp8x4_to_f32(w.y);
    a[4]  = fmaf(m, t.x, a[4]);  a[5]  = fmaf(m, t.y, a[5]);
    a[6]  = fmaf(m, t.z, a[6]);  a[7]  = fmaf(m, t.w, a[7]);
    t = fp8x4_to_f32(w.z);
    a[8]  = fmaf(m, t.x, a[8]);  a[9]  = fmaf(m, t.y, a[9]);
    a[10] = fmaf(m, t.z, a[10]); a[11] = fmaf(m, t.w, a[11]);
    t = fp8x4_to_f32(w.w);
    a[12] = fmaf(m, t.x, a[12]); a[13] = fmaf(m, t.y, a[13]);
    a[14] = fmaf(m, t.z, a[14]); a[15] = fmaf(m, t.w, a[15]);
}

// ---------------- CSR build: XCD-local count + bin, then local fill ----------------
// bucket b = blockIdx&7 -> XCD. Blocks stream the whole edge list, keep their col-range:
// cnt atomics local; matching (r,c) appended to an XCD-local bin via wave-coalesced
// cursor atomic (contiguous writes, dirty in local L2). fill4 replays the bin locally.

__global__ __launch_bounds__(256) void count3_k(const int* __restrict__ row,
                                                const int* __restrict__ col,
                                                int* __restrict__ cnt,
                                                int* __restrict__ bcur,
                                                int2* __restrict__ bbin,
                                                int E, unsigned magic, int cap) {
    int b = blockIdx.x & 7;
    int bi = blockIdx.x >> 3;
    int nb = gridDim.x >> 3;
    int2* bb = bbin + (size_t)b * cap;
    int stride = nb * 1024;
    for (int e0 = (bi * 256 + threadIdx.x) * 4; e0 < E; e0 += stride) {
        if (e0 + 4 <= E) {
            int4 c4 = *(const int4*)&col[e0];
            int4 r4 = *(const int4*)&row[e0];
            int b0 = min(7, (int)__umulhi((unsigned)c4.x, magic));
            int b1 = min(7, (int)__umulhi((unsigned)c4.y, magic));
            int b2 = min(7, (int)__umulhi((unsigned)c4.z, magic));
            int b3 = min(7, (int)__umulhi((unsigned)c4.w, magic));
            if (b0 == b) {
                atomicAdd(&cnt[c4.x], 1);
                int p = atomicAdd(&bcur[b], 1);
                if (p < cap) bb[p] = make_int2(r4.x, c4.x);
            }
            if (b1 == b) {
                atomicAdd(&cnt[c4.y], 1);
                int p = atomicAdd(&bcur[b], 1);
                if (p < cap) bb[p] = make_int2(r4.y, c4.y);
            }
            if (b2 == b) {
                atomicAdd(&cnt[c4.z], 1);
                int p = atomicAdd(&bcur[b], 1);
                if (p < cap) bb[p] = make_int2(r4.z, c4.z);
            }
            if (b3 == b) {
                atomicAdd(&cnt[c4.w], 1);
                int p = atomicAdd(&bcur[b], 1);
                if (p < cap) bb[p] = make_int2(r4.w, c4.w);
            }
        } else {
            for (int e = e0; e < E; e++) {
                int c = col[e];
                if (min(7, (int)__umulhi((unsigned)c, magic)) == b) {
                    atomicAdd(&cnt[c], 1);
                    int p = atomicAdd(&bcur[b], 1);
                    if (p < cap) bb[p] = make_int2(row[e], c);
                }
            }
        }
    }
}

__global__ __launch_bounds__(256) void fill4_k(const int2* __restrict__ bbin,
                                               const int* __restrict__ bcur,
                                               int* __restrict__ cursor,
                                               int* __restrict__ src, int cap) {
    int b = blockIdx.x & 7;
    int bi = blockIdx.x >> 3;
    int nb = gridDim.x >> 3;
    int m = min(bcur[b], cap);
    const int2* bb = bbin + (size_t)b * cap;
    for (int i = bi * 256 + threadIdx.x; i < m; i += nb * 256) {
        int2 rc = bb[i];
        src[atomicAdd(&cursor[rc.y], 1)] = rc.x;
    }
}

// ---------------- scans (scan2 fused into scan3) ----------------

__global__ void scan1_k(const int* __restrict__ cnt, int* __restrict__ offs,
                        float* __restrict__ dinv, int* __restrict__ bsum, int n) {
    __shared__ int s[1024];
    int tid = threadIdx.x;
    int i = blockIdx.x * 1024 + tid;
    int v = (i < n) ? cnt[i] : 0;
    s[tid] = v;
    __syncthreads();
    for (int off = 1; off < 1024; off <<= 1) {
        int t = (tid >= off) ? s[tid - off] : 0;
        __syncthreads();
        s[tid] += t;
        __syncthreads();
    }
    if (i < n) {
        offs[i] = s[tid] - v;
        dinv[i] = rsqrtf((float)(v + 1));
    }
    if (tid == 1023) bsum[blockIdx.x] = s[1023];
}

// offs[i] += prefix(bsum[0..block)); writes cursor copy; handles i==n. NB <= 128.
__global__ void scan3_k(int* __restrict__ offs, int* __restrict__ cursor,
                        const int* __restrict__ bsum, int nbsum, int n, int E) {
    __shared__ int sred[128];
    int tid = threadIdx.x;
    if (tid < 128)
        sred[tid] = (tid < nbsum && tid < blockIdx.x) ? bsum[tid] : 0;
    __syncthreads();
    for (int s = 64; s > 0; s >>= 1) {
        if (tid < s) sred[tid] += sred[tid + s];
        __syncthreads();
    }
    int base = sred[0];
    int i = blockIdx.x * 1024 + tid;
    if (i < n) {
        int o = offs[i] + base;
        offs[i] = o;
        cursor[i] = o;
    }
    if (i == n) offs[n] = E;
}

// ---------------- W fragment prep (both weights, one launch) ----------------
// slot = (ct*4+ks)*64 + lane; 8 bf16: W[ks*32+(lane>>4)*8+j][ct*16+(lane&15)]

__global__ void wprep2_k(const float* __restrict__ W1, const float* __restrict__ W2,
                         unsigned int* __restrict__ wf1, unsigned int* __restrict__ wf2) {
    int half = blockIdx.x >> 3;
    const float* W = half ? W2 : W1;
    unsigned int* wfg = half ? wf2 : wf1;
    int slot = (blockIdx.x & 7) * 256 + threadIdx.x;   // 0..2047
    int l = slot & 63;
    int ks = (slot >> 6) & 3;
    int ct = slot >> 8;
    int n0 = ct * 16 + (l & 15);
    int k0 = ks * 32 + (l >> 4) * 8;
    unsigned short t[8];
#pragma unroll
    for (int j = 0; j < 8; j++) t[j] = f2bf(W[(k0 + j) * F + n0]);
    uint4 v;
    v.x = (unsigned)t[0] | ((unsigned)t[1] << 16);
    v.y = (unsigned)t[2] | ((unsigned)t[3] << 16);
    v.z = (unsigned)t[4] | ((unsigned)t[5] << 16);
    v.w = (unsigned)t[6] | ((unsigned)t[7] << 16);
    ((uint4*)wfg)[slot] = v;
}

// ---------------- MFMA GEMM: Y8[r][128] = fp8( dinv[r] * (X[r,:] @ W) ) ----------------

template <int FP8IN>
__global__ __launch_bounds__(256) void gemm_mfma_k(const void* __restrict__ Xin,
                                                   const unsigned int* __restrict__ wfg,
                                                   const float* __restrict__ dinv,
                                                   unsigned int* __restrict__ Y8, int n) {
    __shared__ unsigned short wf[16384];     // 32 KB fragment-ordered W
    __shared__ float Dt[4][16 * 132];        // per-wave D tile, padded
    for (int i = threadIdx.x; i < 2048; i += 256)
        ((uint4*)wf)[i] = ((const uint4*)wfg)[i];
    __syncthreads();

    int l = threadIdx.x & 63;
    int w = threadIdx.x >> 6;
    const float* Xf = (const float*)Xin;
    const uint2* X8 = (const uint2*)Xin;

    for (int t = 0; t < 2; t++) {
        int rbase = blockIdx.x * 128 + w * 32 + t * 16;
        int arow = rbase + (l & 15);
        if (arow > n - 1) arow = n - 1;

        short8 af[4];
#pragma unroll
        for (int ks = 0; ks < 4; ks++) {
            short8 f;
            if (FP8IN) {
                uint2 v = X8[(size_t)arow * 16 + ks * 4 + (l >> 4)];
                float4 lo = fp8x4_to_f32(v.x);
                float4 hi = fp8x4_to_f32(v.y);
                f[0] = (short)f2bf(lo.x); f[1] = (short)f2bf(lo.y);
                f[2] = (short)f2bf(lo.z); f[3] = (short)f2bf(lo.w);
                f[4] = (short)f2bf(hi.x); f[5] = (short)f2bf(hi.y);
                f[6] = (short)f2bf(hi.z); f[7] = (short)f2bf(hi.w);
            } else {
                const float* xr = Xf + (size_t)arow * F + ks * 32 + (l >> 4) * 8;
                float4 a0 = *(const float4*)xr;
                float4 a1 = *(const float4*)(xr + 4);
                f[0] = (short)f2bf(a0.x); f[1] = (short)f2bf(a0.y);
                f[2] = (short)f2bf(a0.z); f[3] = (short)f2bf(a0.w);
                f[4] = (short)f2bf(a1.x); f[5] = (short)f2bf(a1.y);
                f[6] = (short)f2bf(a1.z); f[7] = (short)f2bf(a1.w);
            }
            af[ks] = f;
        }

        f32x4 acc[8];
#pragma unroll
        for (int ct = 0; ct < 8; ct++) acc[ct] = (f32x4){0.f, 0.f, 0.f, 0.f};

#pragma unroll
        for (int ct = 0; ct < 8; ct++) {
#pragma unroll
            for (int ks = 0; ks < 4; ks++) {
                short8 bf = *(const short8*)&wf[((((ct << 2) | ks) << 6) + l) * 8];
                acc[ct] = __builtin_amdgcn_mfma_f32_16x16x32_bf16(af[ks], bf, acc[ct], 0, 0, 0);
            }
        }

        float* dt = Dt[w];
#pragma unroll
        for (int ct = 0; ct < 8; ct++)
#pragma unroll
            for (int r = 0; r < 4; r++)
                dt[((l >> 4) * 4 + r) * 132 + ct * 16 + (l & 15)] = acc[ct][r];
        __syncthreads();

#pragma unroll
        for (int i = 0; i < 8; i++) {
            int wordid = l + i * 64;
            int rrow = wordid >> 5;
            int wc = wordid & 31;
            int grow = rbase + rrow;
            if (grow < n) {
                float sc = dinv[grow];
                const float* p = &dt[rrow * 132 + wc * 4];
                unsigned int pk = f32x4_to_fp8(sc * p[0], sc * p[1], sc * p[2], sc * p[3]);
                __builtin_nontemporal_store(pk, &Y8[(size_t)grow * 32 + wc]);
            }
        }
        __syncthreads();
    }
}

// ---------------- Aggregation: 8-lane group per node, 8-deep pipelined gathers ----------------

template <int WRITE_H>
__global__ __launch_bounds__(256) void agg_k(const uint4* __restrict__ Y4,
                                             const float* __restrict__ dinv,
                                             const int* __restrict__ offs,
                                             const int* __restrict__ src,
                                             const float* __restrict__ bias,
                                             uint4* __restrict__ H4,
                                             float* __restrict__ gaccP, int n) {
    int l8 = threadIdx.x & 7;          // lane in group: 16 feats
    int grp = threadIdx.x >> 3;        // 0..31: node slot
    int g = blockIdx.x * 32 + grp;

    float a[16];
#pragma unroll
    for (int i = 0; i < 16; i++) a[i] = 0.f;
    float dv = 0.f;

    if (g < n) {
        uint4 selfw = Y4[(size_t)g * 8 + l8];   // issue early
        int s = offs[g], e = offs[g + 1];
        dv = dinv[g];
        acc16(a, selfw, 1.f);

        if (s < e) {
            int em1 = e - 1;
            int u[8], nu[8];
#pragma unroll
            for (int i = 0; i < 8; i++) u[i] = src[min(s + i, em1)];

            for (int base = s; base < e; base += 8) {
                uint4 wv[8];
#pragma unroll
                for (int i = 0; i < 8; i++) wv[i] = Y4[(size_t)u[i] * 8 + l8];
                int nb = base + 8;
                if (nb < e) {
#pragma unroll
                    for (int i = 0; i < 8; i++) nu[i] = src[min(nb + i, em1)];
                }
                acc16(a, wv[0], 1.f);
#pragma unroll
                for (int i = 1; i < 8; i++) {
                    float m = (base + i <= em1) ? 1.f : 0.f;
                    acc16(a, wv[i], m);
                }
#pragma unroll
                for (int i = 0; i < 8; i++) u[i] = nu[i];
            }
        }
    }

    float h[16];
    if (g < n) {
        const float4* b4 = (const float4*)bias;
#pragma unroll
        for (int j = 0; j < 4; j++) {
            float4 b = b4[l8 * 4 + j];
            h[j * 4 + 0] = fmaxf(fmaf(dv, a[j * 4 + 0], b.x), 0.f);
            h[j * 4 + 1] = fmaxf(fmaf(dv, a[j * 4 + 1], b.y), 0.f);
            h[j * 4 + 2] = fmaxf(fmaf(dv, a[j * 4 + 2], b.z), 0.f);
            h[j * 4 + 3] = fmaxf(fmaf(dv, a[j * 4 + 3], b.w), 0.f);
        }
    } else {
#pragma unroll
        for (int i = 0; i < 16; i++) h[i] = 0.f;
    }

    if (WRITE_H) {
        if (g < n) {
            uint4 o;
            o.x = f32x4_to_fp8(h[0],  h[1],  h[2],  h[3]);
            o.y = f32x4_to_fp8(h[4],  h[5],  h[6],  h[7]);
            o.z = f32x4_to_fp8(h[8],  h[9],  h[10], h[11]);
            o.w = f32x4_to_fp8(h[12], h[13], h[14], h[15]);
            H4[(size_t)g * 8 + l8] = o;
        }
    } else {
#pragma unroll
        for (int i = 0; i < 16; i++) {
            h[i] += __shfl_xor(h[i], 8);
            h[i] += __shfl_xor(h[i], 16);
            h[i] += __shfl_xor(h[i], 32);
        }
        __shared__ float red[4 * 128];
        int w = threadIdx.x >> 6;
        int lane = threadIdx.x & 63;
        if (lane < 8) {
#pragma unroll
            for (int i = 0; i < 16; i++) red[w * 128 + lane * 16 + i] = h[i];
        }
        __syncthreads();
        if (threadIdx.x < 128) {
            float ssum = red[threadIdx.x] + red[128 + threadIdx.x] +
                         red[256 + threadIdx.x] + red[384 + threadIdx.x];
            atomicAdd(&gaccP[(blockIdx.x & 31) * 128 + threadIdx.x], ssum);
        }
    }
}

// ---------------- Final: reduce 32 pool stripes; out[a] = sum_k mean_k * Wl[k][a] + bl[a] ----

__global__ void final_k(const float* __restrict__ gaccP, const float* __restrict__ Wl,
                        const float* __restrict__ bl, float* __restrict__ out, float invN) {
    __shared__ float gs[128];
    int t = threadIdx.x;
    if (t < 128) {
        float s = 0.f;
#pragma unroll
        for (int c = 0; c < 32; c++) s += gaccP[c * 128 + t];
        gs[t] = s * invN;
    }
    __syncthreads();
    if (t < 16) {
        float s = bl[t];
        for (int k = 0; k < 128; k++) s = fmaf(gs[k], Wl[k * 16 + t], s);
        out[t] = s;
    }
}

extern "C" void kernel_launch(void* const* d_in, const int* in_sizes, int n_in,
                              void* d_out, int out_size, void* d_ws, size_t ws_size,
                              hipStream_t stream) {
    const float* x  = (const float*)d_in[0];
    const int*   ei = (const int*)d_in[1];
    const float* W1 = (const float*)d_in[2];
    const float* b1 = (const float*)d_in[3];
    const float* W2 = (const float*)d_in[4];
    const float* b2 = (const float*)d_in[5];
    const float* Wl = (const float*)d_in[6];
    const float* bl = (const float*)d_in[7];

    int N = in_sizes[0] / F;
    int E = in_sizes[1] / 2;
    const int* row = ei;
    const int* col = ei + E;

    char* ws = (char*)d_ws;
    size_t off = 0;
    auto alloc = [&](size_t bytes) -> void* {
        void* p = ws + off;
        off = (off + bytes + 255) & ~(size_t)255;
        return p;
    };
    int cap = E / NBUCK + 16384;   // ~38-sigma slack for uniform random cols

    int*          cnt    = (int*)          alloc((size_t)N * 4);
    int*          offs   = (int*)          alloc((size_t)(N + 1) * 4);
    int*          cursor = (int*)          alloc((size_t)N * 4);
    float*        dinv   = (float*)        alloc((size_t)N * 4);
    int*          bsum   = (int*)          alloc(1024 * 4);
    int*          srcb   = (int*)          alloc((size_t)E * 4);
    unsigned int* ybf8   = (unsigned int*) alloc((size_t)N * F);
    unsigned int* hbf8   = (unsigned int*) alloc((size_t)N * F);
    float*        gaccP  = (float*)        alloc(32 * 128 * 4);
    unsigned int* wf1g   = (unsigned int*) alloc(2048 * 16);
    unsigned int* wf2g   = (unsigned int*) alloc(2048 * 16);
    int*          bcur   = (int*)          alloc(NBUCK * 4);
    int2*         bbin   = (int2*)         alloc((size_t)NBUCK * cap * 8);

    hipMemsetAsync(cnt, 0, (size_t)N * 4, stream);
    hipMemsetAsync(gaccP, 0, 32 * 128 * 4, stream);
    hipMemsetAsync(bcur, 0, NBUCK * 4, stream);

    int bsize = (N + NBUCK - 1) / NBUCK;
    unsigned magic = (unsigned)((0x100000000ull + bsize - 1) / (unsigned long long)bsize);

    int NB = (N + 1023) / 1024;
    wprep2_k<<<16, 256, 0, stream>>>(W1, W2, wf1g, wf2g);
    count3_k<<<2048, 256, 0, stream>>>(row, col, cnt, bcur, bbin, E, magic, cap);
    scan1_k<<<NB, 1024, 0, stream>>>(cnt, offs, dinv, bsum, N);
    scan3_k<<<(N + 1024) / 1024, 1024, 0, stream>>>(offs, cursor, bsum, NB, N, E);
    fill4_k<<<2048, 256, 0, stream>>>(bbin, bcur, cursor, srcb, cap);

    int GEMM_BLOCKS = (N + 127) / 128;
    int AGG_BLOCKS = (N + 31) / 32;

    gemm_mfma_k<0><<<GEMM_BLOCKS, 256, 0, stream>>>(x, wf1g, dinv, ybf8, N);
    agg_k<1><<<AGG_BLOCKS, 256, 0, stream>>>((const uint4*)ybf8, dinv, offs, srcb, b1,
                                             (uint4*)hbf8, nullptr, N);
    gemm_mfma_k<1><<<GEMM_BLOCKS, 256, 0, stream>>>(hbf8, wf2g, dinv, ybf8, N);
    agg_k<0><<<AGG_BLOCKS, 256, 0, stream>>>((const uint4*)ybf8, dinv, offs, srcb, b2,
                                             nullptr, gaccP, N);
    final_k<<<1, 128, 0, stream>>>(gaccP, Wl, bl, (float*)d_out, 1.0f / (float)N);
}

// Round 13
// 266.611 us; speedup vs baseline: 9.2825x; 9.2825x over previous
//
#include <hip/hip_runtime.h>
#include <hip/hip_bf16.h>

#define F 128
#define NBUCK 8

typedef float floatx2 __attribute__((ext_vector_type(2)));
typedef float f32x4 __attribute__((ext_vector_type(4)));
typedef short short8 __attribute__((ext_vector_type(8)));

static __device__ __forceinline__ unsigned short f2bf(float f) {
    unsigned int u = __float_as_uint(f);
    unsigned int r = (u + 0x7fffu + ((u >> 16) & 1u)) >> 16;   // RTN-even
    return (unsigned short)r;
}

static __device__ __forceinline__ float4 fp8x4_to_f32(unsigned int w) {
    floatx2 lo = __builtin_amdgcn_cvt_pk_f32_fp8((int)w, false);
    floatx2 hi = __builtin_amdgcn_cvt_pk_f32_fp8((int)w, true);
    return make_float4(lo[0], lo[1], hi[0], hi[1]);
}

static __device__ __forceinline__ unsigned int f32x4_to_fp8(float a, float b, float c, float d) {
    int w = 0;
    w = __builtin_amdgcn_cvt_pk_fp8_f32(a, b, w, false);
    w = __builtin_amdgcn_cvt_pk_fp8_f32(c, d, w, true);
    return (unsigned int)w;
}

// decode 16 fp8 (uint4) and masked-accumulate into a[16]
static __device__ __forceinline__ void acc16(float* a, uint4 w, float m) {
    float4 t;
    t = fp8x4_to_f32(w.x);
    a[0]  = fmaf(m, t.x, a[0]);  a[1]  = fmaf(m, t.y, a[1]);
    a[2]  = fmaf(m, t.z, a[2]);  a[3]  = fmaf(m, t.w, a[3]);
    t = fp8x4_to_f32(w.y);
    a[4]  = fmaf(m, t.x, a[4]);  a[5]  = fmaf(m, t.y, a[5]);
    a[6]  = fmaf(m, t.z, a[6]);  a[7]  = fmaf(m, t.w, a[7]);
    t = fp8x4_to_f32(w.z);
    a[8]  = fmaf(m, t.x, a[8]);  a[9]  = fmaf(m, t.y, a[9]);
    a[10] = fmaf(m, t.z, a[10]); a[11] = fmaf(m, t.w, a[11]);
    t = fp8x4_to_f32(w.w);
    a[12] = fmaf(m, t.x, a[12]); a[13] = fmaf(m, t.y, a[13]);
    a[14] = fmaf(m, t.z, a[14]); a[15] = fmaf(m, t.w, a[15]);
}

// ---------------- CSR build: XCD-local via full-stream read + range mask (R11 proven) ------
// bucket b = blockIdx&7 -> XCD under round-robin dispatch. Blocks stream the whole edge
// list (LLC-resident) but touch only their node range: cnt/cursor slice (~50KB) and src
// window (~800KB) stay in one XCD's L2. Scattered atomics spread over 12.5K addresses.

__global__ __launch_bounds__(256) void count3_k(const int* __restrict__ col,
                                                int* __restrict__ cnt,
                                                int E, unsigned magic) {
    int b = blockIdx.x & 7;
    int bi = blockIdx.x >> 3;
    int nb = gridDim.x >> 3;
    int stride = nb * 1024;
    for (int e0 = (bi * 256 + threadIdx.x) * 4; e0 < E; e0 += stride) {
        if (e0 + 4 <= E) {
            int4 c4 = *(const int4*)&col[e0];
            int b0 = min(7, (int)__umulhi((unsigned)c4.x, magic));
            int b1 = min(7, (int)__umulhi((unsigned)c4.y, magic));
            int b2 = min(7, (int)__umulhi((unsigned)c4.z, magic));
            int b3 = min(7, (int)__umulhi((unsigned)c4.w, magic));
            if (b0 == b) atomicAdd(&cnt[c4.x], 1);
            if (b1 == b) atomicAdd(&cnt[c4.y], 1);
            if (b2 == b) atomicAdd(&cnt[c4.z], 1);
            if (b3 == b) atomicAdd(&cnt[c4.w], 1);
        } else {
            for (int e = e0; e < E; e++) {
                int c = col[e];
                if (min(7, (int)__umulhi((unsigned)c, magic)) == b)
                    atomicAdd(&cnt[c], 1);
            }
        }
    }
}

__global__ __launch_bounds__(256) void fill3_k(const int* __restrict__ row,
                                               const int* __restrict__ col,
                                               int* __restrict__ cursor,
                                               int* __restrict__ src,
                                               int E, unsigned magic) {
    int b = blockIdx.x & 7;
    int bi = blockIdx.x >> 3;
    int nb = gridDim.x >> 3;
    int stride = nb * 1024;
    for (int e0 = (bi * 256 + threadIdx.x) * 4; e0 < E; e0 += stride) {
        if (e0 + 4 <= E) {
            int4 c4 = *(const int4*)&col[e0];
            int4 r4 = *(const int4*)&row[e0];
            int b0 = min(7, (int)__umulhi((unsigned)c4.x, magic));
            int b1 = min(7, (int)__umulhi((unsigned)c4.y, magic));
            int b2 = min(7, (int)__umulhi((unsigned)c4.z, magic));
            int b3 = min(7, (int)__umulhi((unsigned)c4.w, magic));
            if (b0 == b) src[atomicAdd(&cursor[c4.x], 1)] = r4.x;
            if (b1 == b) src[atomicAdd(&cursor[c4.y], 1)] = r4.y;
            if (b2 == b) src[atomicAdd(&cursor[c4.z], 1)] = r4.z;
            if (b3 == b) src[atomicAdd(&cursor[c4.w], 1)] = r4.w;
        } else {
            for (int e = e0; e < E; e++) {
                int c = col[e];
                if (min(7, (int)__umulhi((unsigned)c, magic)) == b)
                    src[atomicAdd(&cursor[c], 1)] = row[e];
            }
        }
    }
}

// ---------------- scans (scan2 fused into scan3) ----------------

__global__ void scan1_k(const int* __restrict__ cnt, int* __restrict__ offs,
                        float* __restrict__ dinv, int* __restrict__ bsum, int n) {
    __shared__ int s[1024];
    int tid = threadIdx.x;
    int i = blockIdx.x * 1024 + tid;
    int v = (i < n) ? cnt[i] : 0;
    s[tid] = v;
    __syncthreads();
    for (int off = 1; off < 1024; off <<= 1) {
        int t = (tid >= off) ? s[tid - off] : 0;
        __syncthreads();
        s[tid] += t;
        __syncthreads();
    }
    if (i < n) {
        offs[i] = s[tid] - v;
        dinv[i] = rsqrtf((float)(v + 1));
    }
    if (tid == 1023) bsum[blockIdx.x] = s[1023];
}

// offs[i] += prefix(bsum[0..block)); writes cursor copy; handles i==n. NB <= 128.
__global__ void scan3_k(int* __restrict__ offs, int* __restrict__ cursor,
                        const int* __restrict__ bsum, int nbsum, int n, int E) {
    __shared__ int sred[128];
    int tid = threadIdx.x;
    if (tid < 128)
        sred[tid] = (tid < nbsum && tid < blockIdx.x) ? bsum[tid] : 0;
    __syncthreads();
    for (int s = 64; s > 0; s >>= 1) {
        if (tid < s) sred[tid] += sred[tid + s];
        __syncthreads();
    }
    int base = sred[0];
    int i = blockIdx.x * 1024 + tid;
    if (i < n) {
        int o = offs[i] + base;
        offs[i] = o;
        cursor[i] = o;
    }
    if (i == n) offs[n] = E;
}

// ---------------- W fragment prep (both weights, one launch) ----------------
// slot = (ct*4+ks)*64 + lane; 8 bf16: W[ks*32+(lane>>4)*8+j][ct*16+(lane&15)]

__global__ void wprep2_k(const float* __restrict__ W1, const float* __restrict__ W2,
                         unsigned int* __restrict__ wf1, unsigned int* __restrict__ wf2) {
    int half = blockIdx.x >> 3;
    const float* W = half ? W2 : W1;
    unsigned int* wfg = half ? wf2 : wf1;
    int slot = (blockIdx.x & 7) * 256 + threadIdx.x;   // 0..2047
    int l = slot & 63;
    int ks = (slot >> 6) & 3;
    int ct = slot >> 8;
    int n0 = ct * 16 + (l & 15);
    int k0 = ks * 32 + (l >> 4) * 8;
    unsigned short t[8];
#pragma unroll
    for (int j = 0; j < 8; j++) t[j] = f2bf(W[(k0 + j) * F + n0]);
    uint4 v;
    v.x = (unsigned)t[0] | ((unsigned)t[1] << 16);
    v.y = (unsigned)t[2] | ((unsigned)t[3] << 16);
    v.z = (unsigned)t[4] | ((unsigned)t[5] << 16);
    v.w = (unsigned)t[6] | ((unsigned)t[7] << 16);
    ((uint4*)wfg)[slot] = v;
}

// ---------------- MFMA GEMM: Y8[r][128] = fp8( dinv[r] * (X[r,:] @ W) ) ----------------

template <int FP8IN>
__global__ __launch_bounds__(256) void gemm_mfma_k(const void* __restrict__ Xin,
                                                   const unsigned int* __restrict__ wfg,
                                                   const float* __restrict__ dinv,
                                                   unsigned int* __restrict__ Y8, int n) {
    __shared__ unsigned short wf[16384];     // 32 KB fragment-ordered W
    __shared__ float Dt[4][16 * 132];        // per-wave D tile, padded
    for (int i = threadIdx.x; i < 2048; i += 256)
        ((uint4*)wf)[i] = ((const uint4*)wfg)[i];
    __syncthreads();

    int l = threadIdx.x & 63;
    int w = threadIdx.x >> 6;
    const float* Xf = (const float*)Xin;
    const uint2* X8 = (const uint2*)Xin;

    for (int t = 0; t < 2; t++) {
        int rbase = blockIdx.x * 128 + w * 32 + t * 16;
        int arow = rbase + (l & 15);
        if (arow > n - 1) arow = n - 1;

        short8 af[4];
#pragma unroll
        for (int ks = 0; ks < 4; ks++) {
            short8 f;
            if (FP8IN) {
                uint2 v = X8[(size_t)arow * 16 + ks * 4 + (l >> 4)];
                float4 lo = fp8x4_to_f32(v.x);
                float4 hi = fp8x4_to_f32(v.y);
                f[0] = (short)f2bf(lo.x); f[1] = (short)f2bf(lo.y);
                f[2] = (short)f2bf(lo.z); f[3] = (short)f2bf(lo.w);
                f[4] = (short)f2bf(hi.x); f[5] = (short)f2bf(hi.y);
                f[6] = (short)f2bf(hi.z); f[7] = (short)f2bf(hi.w);
            } else {
                const float* xr = Xf + (size_t)arow * F + ks * 32 + (l >> 4) * 8;
                float4 a0 = *(const float4*)xr;
                float4 a1 = *(const float4*)(xr + 4);
                f[0] = (short)f2bf(a0.x); f[1] = (short)f2bf(a0.y);
                f[2] = (short)f2bf(a0.z); f[3] = (short)f2bf(a0.w);
                f[4] = (short)f2bf(a1.x); f[5] = (short)f2bf(a1.y);
                f[6] = (short)f2bf(a1.z); f[7] = (short)f2bf(a1.w);
            }
            af[ks] = f;
        }

        f32x4 acc[8];
#pragma unroll
        for (int ct = 0; ct < 8; ct++) acc[ct] = (f32x4){0.f, 0.f, 0.f, 0.f};

#pragma unroll
        for (int ct = 0; ct < 8; ct++) {
#pragma unroll
            for (int ks = 0; ks < 4; ks++) {
                short8 bf = *(const short8*)&wf[((((ct << 2) | ks) << 6) + l) * 8];
                acc[ct] = __builtin_amdgcn_mfma_f32_16x16x32_bf16(af[ks], bf, acc[ct], 0, 0, 0);
            }
        }

        float* dt = Dt[w];
#pragma unroll
        for (int ct = 0; ct < 8; ct++)
#pragma unroll
            for (int r = 0; r < 4; r++)
                dt[((l >> 4) * 4 + r) * 132 + ct * 16 + (l & 15)] = acc[ct][r];
        __syncthreads();

#pragma unroll
        for (int i = 0; i < 8; i++) {
            int wordid = l + i * 64;
            int rrow = wordid >> 5;
            int wc = wordid & 31;
            int grow = rbase + rrow;
            if (grow < n) {
                float sc = dinv[grow];
                const float* p = &dt[rrow * 132 + wc * 4];
                unsigned int pk = f32x4_to_fp8(sc * p[0], sc * p[1], sc * p[2], sc * p[3]);
                __builtin_nontemporal_store(pk, &Y8[(size_t)grow * 32 + wc]);
            }
        }
        __syncthreads();
    }
}

// ---------------- Aggregation: 8-lane group per node, 8-deep pipelined gathers ----------------

template <int WRITE_H>
__global__ __launch_bounds__(256) void agg_k(const uint4* __restrict__ Y4,
                                             const float* __restrict__ dinv,
                                             const int* __restrict__ offs,
                                             const int* __restrict__ src,
                                             const float* __restrict__ bias,
                                             uint4* __restrict__ H4,
                                             float* __restrict__ gaccP, int n) {
    int l8 = threadIdx.x & 7;          // lane in group: 16 feats
    int grp = threadIdx.x >> 3;        // 0..31: node slot
    int g = blockIdx.x * 32 + grp;

    float a[16];
#pragma unroll
    for (int i = 0; i < 16; i++) a[i] = 0.f;
    float dv = 0.f;

    if (g < n) {
        uint4 selfw = Y4[(size_t)g * 8 + l8];   // issue early
        int s = offs[g], e = offs[g + 1];
        dv = dinv[g];
        acc16(a, selfw, 1.f);

        if (s < e) {
            int em1 = e - 1;
            int u[8], nu[8];
#pragma unroll
            for (int i = 0; i < 8; i++) u[i] = src[min(s + i, em1)];

            for (int base = s; base < e; base += 8) {
                uint4 wv[8];
#pragma unroll
                for (int i = 0; i < 8; i++) wv[i] = Y4[(size_t)u[i] * 8 + l8];
                int nb = base + 8;
                if (nb < e) {
#pragma unroll
                    for (int i = 0; i < 8; i++) nu[i] = src[min(nb + i, em1)];
                }
                acc16(a, wv[0], 1.f);
#pragma unroll
                for (int i = 1; i < 8; i++) {
                    float m = (base + i <= em1) ? 1.f : 0.f;
                    acc16(a, wv[i], m);
                }
#pragma unroll
                for (int i = 0; i < 8; i++) u[i] = nu[i];
            }
        }
    }

    float h[16];
    if (g < n) {
        const float4* b4 = (const float4*)bias;
#pragma unroll
        for (int j = 0; j < 4; j++) {
            float4 b = b4[l8 * 4 + j];
            h[j * 4 + 0] = fmaxf(fmaf(dv, a[j * 4 + 0], b.x), 0.f);
            h[j * 4 + 1] = fmaxf(fmaf(dv, a[j * 4 + 1], b.y), 0.f);
            h[j * 4 + 2] = fmaxf(fmaf(dv, a[j * 4 + 2], b.z), 0.f);
            h[j * 4 + 3] = fmaxf(fmaf(dv, a[j * 4 + 3], b.w), 0.f);
        }
    } else {
#pragma unroll
        for (int i = 0; i < 16; i++) h[i] = 0.f;
    }

    if (WRITE_H) {
        if (g < n) {
            uint4 o;
            o.x = f32x4_to_fp8(h[0],  h[1],  h[2],  h[3]);
            o.y = f32x4_to_fp8(h[4],  h[5],  h[6],  h[7]);
            o.z = f32x4_to_fp8(h[8],  h[9],  h[10], h[11]);
            o.w = f32x4_to_fp8(h[12], h[13], h[14], h[15]);
            H4[(size_t)g * 8 + l8] = o;
        }
    } else {
#pragma unroll
        for (int i = 0; i < 16; i++) {
            h[i] += __shfl_xor(h[i], 8);
            h[i] += __shfl_xor(h[i], 16);
            h[i] += __shfl_xor(h[i], 32);
        }
        __shared__ float red[4 * 128];
        int w = threadIdx.x >> 6;
        int lane = threadIdx.x & 63;
        if (lane < 8) {
#pragma unroll
            for (int i = 0; i < 16; i++) red[w * 128 + lane * 16 + i] = h[i];
        }
        __syncthreads();
        if (threadIdx.x < 128) {
            float ssum = red[threadIdx.x] + red[128 + threadIdx.x] +
                         red[256 + threadIdx.x] + red[384 + threadIdx.x];
            atomicAdd(&gaccP[(blockIdx.x & 31) * 128 + threadIdx.x], ssum);
        }
    }
}

// ---------------- Final: reduce 32 pool stripes; out[a] = sum_k mean_k * Wl[k][a] + bl[a] ----

__global__ void final_k(const float* __restrict__ gaccP, const float* __restrict__ Wl,
                        const float* __restrict__ bl, float* __restrict__ out, float invN) {
    __shared__ float gs[128];
    int t = threadIdx.x;
    if (t < 128) {
        float s = 0.f;
#pragma unroll
        for (int c = 0; c < 32; c++) s += gaccP[c * 128 + t];
        gs[t] = s * invN;
    }
    __syncthreads();
    if (t < 16) {
        float s = bl[t];
        for (int k = 0; k < 128; k++) s = fmaf(gs[k], Wl[k * 16 + t], s);
        out[t] = s;
    }
}

extern "C" void kernel_launch(void* const* d_in, const int* in_sizes, int n_in,
                              void* d_out, int out_size, void* d_ws, size_t ws_size,
                              hipStream_t stream) {
    const float* x  = (const float*)d_in[0];
    const int*   ei = (const int*)d_in[1];
    const float* W1 = (const float*)d_in[2];
    const float* b1 = (const float*)d_in[3];
    const float* W2 = (const float*)d_in[4];
    const float* b2 = (const float*)d_in[5];
    const float* Wl = (const float*)d_in[6];
    const float* bl = (const float*)d_in[7];

    int N = in_sizes[0] / F;
    int E = in_sizes[1] / 2;
    const int* row = ei;
    const int* col = ei + E;

    char* ws = (char*)d_ws;
    size_t off = 0;
    auto alloc = [&](size_t bytes) -> void* {
        void* p = ws + off;
        off = (off + bytes + 255) & ~(size_t)255;
        return p;
    };
    int*          cnt    = (int*)          alloc((size_t)N * 4);
    int*          offs   = (int*)          alloc((size_t)(N + 1) * 4);
    int*          cursor = (int*)          alloc((size_t)N * 4);
    float*        dinv   = (float*)        alloc((size_t)N * 4);
    int*          bsum   = (int*)          alloc(1024 * 4);
    int*          srcb   = (int*)          alloc((size_t)E * 4);
    unsigned int* ybf8   = (unsigned int*) alloc((size_t)N * F);
    unsigned int* hbf8   = (unsigned int*) alloc((size_t)N * F);
    float*        gaccP  = (float*)        alloc(32 * 128 * 4);
    unsigned int* wf1g   = (unsigned int*) alloc(2048 * 16);
    unsigned int* wf2g   = (unsigned int*) alloc(2048 * 16);

    hipMemsetAsync(cnt, 0, (size_t)N * 4, stream);
    hipMemsetAsync(gaccP, 0, 32 * 128 * 4, stream);

    int bsize = (N + NBUCK - 1) / NBUCK;
    unsigned magic = (unsigned)((0x100000000ull + bsize - 1) / (unsigned long long)bsize);

    int NB = (N + 1023) / 1024;
    wprep2_k<<<16, 256, 0, stream>>>(W1, W2, wf1g, wf2g);
    count3_k<<<2048, 256, 0, stream>>>(col, cnt, E, magic);
    scan1_k<<<NB, 1024, 0, stream>>>(cnt, offs, dinv, bsum, N);
    scan3_k<<<(N + 1024) / 1024, 1024, 0, stream>>>(offs, cursor, bsum, NB, N, E);
    fill3_k<<<2048, 256, 0, stream>>>(row, col, cursor, srcb, E, magic);

    int GEMM_BLOCKS = (N + 127) / 128;
    int AGG_BLOCKS = (N + 31) / 32;

    gemm_mfma_k<0><<<GEMM_BLOCKS, 256, 0, stream>>>(x, wf1g, dinv, ybf8, N);
    agg_k<1><<<AGG_BLOCKS, 256, 0, stream>>>((const uint4*)ybf8, dinv, offs, srcb, b1,
                                             (uint4*)hbf8, nullptr, N);
    gemm_mfma_k<1><<<GEMM_BLOCKS, 256, 0, stream>>>(hbf8, wf2g, dinv, ybf8, N);
    agg_k<0><<<AGG_BLOCKS, 256, 0, stream>>>((const uint4*)ybf8, dinv, offs, srcb, b2,
                                             nullptr, gaccP, N);
    final_k<<<1, 128, 0, stream>>>(gaccP, Wl, bl, (float*)d_out, 1.0f / (float)N);
}

// Round 14
// 265.999 us; speedup vs baseline: 9.3039x; 1.0023x over previous
//
#include <hip/hip_runtime.h>
#include <hip/hip_bf16.h>

#define F 128
#define NBUCK 8

typedef float floatx2 __attribute__((ext_vector_type(2)));
typedef float f32x4 __attribute__((ext_vector_type(4)));
typedef short short8 __attribute__((ext_vector_type(8)));

static __device__ __forceinline__ unsigned short f2bf(float f) {
    unsigned int u = __float_as_uint(f);
    unsigned int r = (u + 0x7fffu + ((u >> 16) & 1u)) >> 16;   // RTN-even
    return (unsigned short)r;
}

static __device__ __forceinline__ float4 fp8x4_to_f32(unsigned int w) {
    floatx2 lo = __builtin_amdgcn_cvt_pk_f32_fp8((int)w, false);
    floatx2 hi = __builtin_amdgcn_cvt_pk_f32_fp8((int)w, true);
    return make_float4(lo[0], lo[1], hi[0], hi[1]);
}

static __device__ __forceinline__ unsigned int f32x4_to_fp8(float a, float b, float c, float d) {
    int w = 0;
    w = __builtin_amdgcn_cvt_pk_fp8_f32(a, b, w, false);
    w = __builtin_amdgcn_cvt_pk_fp8_f32(c, d, w, true);
    return (unsigned int)w;
}

// decode 16 fp8 (uint4) and masked-accumulate into a[16]
static __device__ __forceinline__ void acc16(float* a, uint4 w, float m) {
    float4 t;
    t = fp8x4_to_f32(w.x);
    a[0]  = fmaf(m, t.x, a[0]);  a[1]  = fmaf(m, t.y, a[1]);
    a[2]  = fmaf(m, t.z, a[2]);  a[3]  = fmaf(m, t.w, a[3]);
    t = fp8x4_to_f32(w.y);
    a[4]  = fmaf(m, t.x, a[4]);  a[5]  = fmaf(m, t.y, a[5]);
    a[6]  = fmaf(m, t.z, a[6]);  a[7]  = fmaf(m, t.w, a[7]);
    t = fp8x4_to_f32(w.z);
    a[8]  = fmaf(m, t.x, a[8]);  a[9]  = fmaf(m, t.y, a[9]);
    a[10] = fmaf(m, t.z, a[10]); a[11] = fmaf(m, t.w, a[11]);
    t = fp8x4_to_f32(w.w);
    a[12] = fmaf(m, t.x, a[12]); a[13] = fmaf(m, t.y, a[13]);
    a[14] = fmaf(m, t.z, a[14]); a[15] = fmaf(m, t.w, a[15]);
}

// ---------------- CSR build: XCD-local via full-stream read + range mask (R11 proven) ------
// bucket b = blockIdx&7 -> XCD under round-robin dispatch. Blocks stream the whole edge
// list (LLC-resident) but touch only their node range: cnt/cursor slice (~50KB) and src
// window (~800KB) stay in one XCD's L2. Scattered atomics spread over 12.5K addresses.

__global__ __launch_bounds__(256) void count3_k(const int* __restrict__ col,
                                                int* __restrict__ cnt,
                                                int E, unsigned magic) {
    int b = blockIdx.x & 7;
    int bi = blockIdx.x >> 3;
    int nb = gridDim.x >> 3;
    int stride = nb * 1024;
    for (int e0 = (bi * 256 + threadIdx.x) * 4; e0 < E; e0 += stride) {
        if (e0 + 4 <= E) {
            int4 c4 = *(const int4*)&col[e0];
            int b0 = min(7, (int)__umulhi((unsigned)c4.x, magic));
            int b1 = min(7, (int)__umulhi((unsigned)c4.y, magic));
            int b2 = min(7, (int)__umulhi((unsigned)c4.z, magic));
            int b3 = min(7, (int)__umulhi((unsigned)c4.w, magic));
            if (b0 == b) atomicAdd(&cnt[c4.x], 1);
            if (b1 == b) atomicAdd(&cnt[c4.y], 1);
            if (b2 == b) atomicAdd(&cnt[c4.z], 1);
            if (b3 == b) atomicAdd(&cnt[c4.w], 1);
        } else {
            for (int e = e0; e < E; e++) {
                int c = col[e];
                if (min(7, (int)__umulhi((unsigned)c, magic)) == b)
                    atomicAdd(&cnt[c], 1);
            }
        }
    }
}

__global__ __launch_bounds__(256) void fill3_k(const int* __restrict__ row,
                                               const int* __restrict__ col,
                                               int* __restrict__ cursor,
                                               int* __restrict__ src,
                                               int E, unsigned magic) {
    int b = blockIdx.x & 7;
    int bi = blockIdx.x >> 3;
    int nb = gridDim.x >> 3;
    int stride = nb * 1024;
    for (int e0 = (bi * 256 + threadIdx.x) * 4; e0 < E; e0 += stride) {
        if (e0 + 4 <= E) {
            int4 c4 = *(const int4*)&col[e0];
            int4 r4 = *(const int4*)&row[e0];
            int b0 = min(7, (int)__umulhi((unsigned)c4.x, magic));
            int b1 = min(7, (int)__umulhi((unsigned)c4.y, magic));
            int b2 = min(7, (int)__umulhi((unsigned)c4.z, magic));
            int b3 = min(7, (int)__umulhi((unsigned)c4.w, magic));
            if (b0 == b) src[atomicAdd(&cursor[c4.x], 1)] = r4.x;
            if (b1 == b) src[atomicAdd(&cursor[c4.y], 1)] = r4.y;
            if (b2 == b) src[atomicAdd(&cursor[c4.z], 1)] = r4.z;
            if (b3 == b) src[atomicAdd(&cursor[c4.w], 1)] = r4.w;
        } else {
            for (int e = e0; e < E; e++) {
                int c = col[e];
                if (min(7, (int)__umulhi((unsigned)c, magic)) == b)
                    src[atomicAdd(&cursor[c], 1)] = row[e];
            }
        }
    }
}

// ---------------- scans (scan2 fused into scan3) ----------------

__global__ void scan1_k(const int* __restrict__ cnt, int* __restrict__ offs,
                        float* __restrict__ dinv, int* __restrict__ bsum, int n) {
    __shared__ int s[1024];
    int tid = threadIdx.x;
    int i = blockIdx.x * 1024 + tid;
    int v = (i < n) ? cnt[i] : 0;
    s[tid] = v;
    __syncthreads();
    for (int off = 1; off < 1024; off <<= 1) {
        int t = (tid >= off) ? s[tid - off] : 0;
        __syncthreads();
        s[tid] += t;
        __syncthreads();
    }
    if (i < n) {
        offs[i] = s[tid] - v;
        dinv[i] = rsqrtf((float)(v + 1));
    }
    if (tid == 1023) bsum[blockIdx.x] = s[1023];
}

// offs[i] += prefix(bsum[0..block)); writes cursor copy; handles i==n. NB <= 128.
__global__ void scan3_k(int* __restrict__ offs, int* __restrict__ cursor,
                        const int* __restrict__ bsum, int nbsum, int n, int E) {
    __shared__ int sred[128];
    int tid = threadIdx.x;
    if (tid < 128)
        sred[tid] = (tid < nbsum && tid < blockIdx.x) ? bsum[tid] : 0;
    __syncthreads();
    for (int s = 64; s > 0; s >>= 1) {
        if (tid < s) sred[tid] += sred[tid + s];
        __syncthreads();
    }
    int base = sred[0];
    int i = blockIdx.x * 1024 + tid;
    if (i < n) {
        int o = offs[i] + base;
        offs[i] = o;
        cursor[i] = o;
    }
    if (i == n) offs[n] = E;
}

// ---------------- W fragment prep (both weights, one launch) ----------------
// slot = (ct*4+ks)*64 + lane; 8 bf16: W[ks*32+(lane>>4)*8+j][ct*16+(lane&15)]

__global__ void wprep2_k(const float* __restrict__ W1, const float* __restrict__ W2,
                         unsigned int* __restrict__ wf1, unsigned int* __restrict__ wf2) {
    int half = blockIdx.x >> 3;
    const float* W = half ? W2 : W1;
    unsigned int* wfg = half ? wf2 : wf1;
    int slot = (blockIdx.x & 7) * 256 + threadIdx.x;   // 0..2047
    int l = slot & 63;
    int ks = (slot >> 6) & 3;
    int ct = slot >> 8;
    int n0 = ct * 16 + (l & 15);
    int k0 = ks * 32 + (l >> 4) * 8;
    unsigned short t[8];
#pragma unroll
    for (int j = 0; j < 8; j++) t[j] = f2bf(W[(k0 + j) * F + n0]);
    uint4 v;
    v.x = (unsigned)t[0] | ((unsigned)t[1] << 16);
    v.y = (unsigned)t[2] | ((unsigned)t[3] << 16);
    v.z = (unsigned)t[4] | ((unsigned)t[5] << 16);
    v.w = (unsigned)t[6] | ((unsigned)t[7] << 16);
    ((uint4*)wfg)[slot] = v;
}

// ---------------- MFMA GEMM: Y8[r][128] = fp8( dinv[r] * (X[r,:] @ W) ) ----------------

template <int FP8IN>
__global__ __launch_bounds__(256) void gemm_mfma_k(const void* __restrict__ Xin,
                                                   const unsigned int* __restrict__ wfg,
                                                   const float* __restrict__ dinv,
                                                   unsigned int* __restrict__ Y8, int n) {
    __shared__ unsigned short wf[16384];     // 32 KB fragment-ordered W
    __shared__ float Dt[4][16 * 132];        // per-wave D tile, padded
    for (int i = threadIdx.x; i < 2048; i += 256)
        ((uint4*)wf)[i] = ((const uint4*)wfg)[i];
    __syncthreads();

    int l = threadIdx.x & 63;
    int w = threadIdx.x >> 6;
    const float* Xf = (const float*)Xin;
    const uint2* X8 = (const uint2*)Xin;

    for (int t = 0; t < 2; t++) {
        int rbase = blockIdx.x * 128 + w * 32 + t * 16;
        int arow = rbase + (l & 15);
        if (arow > n - 1) arow = n - 1;

        short8 af[4];
#pragma unroll
        for (int ks = 0; ks < 4; ks++) {
            short8 f;
            if (FP8IN) {
                uint2 v = X8[(size_t)arow * 16 + ks * 4 + (l >> 4)];
                float4 lo = fp8x4_to_f32(v.x);
                float4 hi = fp8x4_to_f32(v.y);
                f[0] = (short)f2bf(lo.x); f[1] = (short)f2bf(lo.y);
                f[2] = (short)f2bf(lo.z); f[3] = (short)f2bf(lo.w);
                f[4] = (short)f2bf(hi.x); f[5] = (short)f2bf(hi.y);
                f[6] = (short)f2bf(hi.z); f[7] = (short)f2bf(hi.w);
            } else {
                const float* xr = Xf + (size_t)arow * F + ks * 32 + (l >> 4) * 8;
                float4 a0 = *(const float4*)xr;
                float4 a1 = *(const float4*)(xr + 4);
                f[0] = (short)f2bf(a0.x); f[1] = (short)f2bf(a0.y);
                f[2] = (short)f2bf(a0.z); f[3] = (short)f2bf(a0.w);
                f[4] = (short)f2bf(a1.x); f[5] = (short)f2bf(a1.y);
                f[6] = (short)f2bf(a1.z); f[7] = (short)f2bf(a1.w);
            }
            af[ks] = f;
        }

        f32x4 acc[8];
#pragma unroll
        for (int ct = 0; ct < 8; ct++) acc[ct] = (f32x4){0.f, 0.f, 0.f, 0.f};

#pragma unroll
        for (int ct = 0; ct < 8; ct++) {
#pragma unroll
            for (int ks = 0; ks < 4; ks++) {
                short8 bf = *(const short8*)&wf[((((ct << 2) | ks) << 6) + l) * 8];
                acc[ct] = __builtin_amdgcn_mfma_f32_16x16x32_bf16(af[ks], bf, acc[ct], 0, 0, 0);
            }
        }

        float* dt = Dt[w];
#pragma unroll
        for (int ct = 0; ct < 8; ct++)
#pragma unroll
            for (int r = 0; r < 4; r++)
                dt[((l >> 4) * 4 + r) * 132 + ct * 16 + (l & 15)] = acc[ct][r];
        __syncthreads();

#pragma unroll
        for (int i = 0; i < 8; i++) {
            int wordid = l + i * 64;
            int rrow = wordid >> 5;
            int wc = wordid & 31;
            int grow = rbase + rrow;
            if (grow < n) {
                float sc = dinv[grow];
                const float* p = &dt[rrow * 132 + wc * 4];
                unsigned int pk = f32x4_to_fp8(sc * p[0], sc * p[1], sc * p[2], sc * p[3]);
                __builtin_nontemporal_store(pk, &Y8[(size_t)grow * 32 + wc]);
            }
        }
        __syncthreads();
    }
}

// ---------------- Aggregation: 8-lane group per node, 8-deep pipelined gathers ----------------

template <int WRITE_H>
__global__ __launch_bounds__(256) void agg_k(const uint4* __restrict__ Y4,
                                             const float* __restrict__ dinv,
                                             const int* __restrict__ offs,
                                             const int* __restrict__ src,
                                             const float* __restrict__ bias,
                                             uint4* __restrict__ H4,
                                             float* __restrict__ gaccP, int n) {
    int l8 = threadIdx.x & 7;          // lane in group: 16 feats
    int grp = threadIdx.x >> 3;        // 0..31: node slot
    int g = blockIdx.x * 32 + grp;

    float a[16];
#pragma unroll
    for (int i = 0; i < 16; i++) a[i] = 0.f;
    float dv = 0.f;

    if (g < n) {
        uint4 selfw = Y4[(size_t)g * 8 + l8];   // issue early
        int s = offs[g], e = offs[g + 1];
        dv = dinv[g];
        acc16(a, selfw, 1.f);

        if (s < e) {
            int em1 = e - 1;
            int u[8], nu[8];
#pragma unroll
            for (int i = 0; i < 8; i++) u[i] = src[min(s + i, em1)];

            for (int base = s; base < e; base += 8) {
                uint4 wv[8];
#pragma unroll
                for (int i = 0; i < 8; i++) wv[i] = Y4[(size_t)u[i] * 8 + l8];
                int nb = base + 8;
                if (nb < e) {
#pragma unroll
                    for (int i = 0; i < 8; i++) nu[i] = src[min(nb + i, em1)];
                }
                acc16(a, wv[0], 1.f);
#pragma unroll
                for (int i = 1; i < 8; i++) {
                    float m = (base + i <= em1) ? 1.f : 0.f;
                    acc16(a, wv[i], m);
                }
#pragma unroll
                for (int i = 0; i < 8; i++) u[i] = nu[i];
            }
        }
    }

    float h[16];
    if (g < n) {
        const float4* b4 = (const float4*)bias;
#pragma unroll
        for (int j = 0; j < 4; j++) {
            float4 b = b4[l8 * 4 + j];
            h[j * 4 + 0] = fmaxf(fmaf(dv, a[j * 4 + 0], b.x), 0.f);
            h[j * 4 + 1] = fmaxf(fmaf(dv, a[j * 4 + 1], b.y), 0.f);
            h[j * 4 + 2] = fmaxf(fmaf(dv, a[j * 4 + 2], b.z), 0.f);
            h[j * 4 + 3] = fmaxf(fmaf(dv, a[j * 4 + 3], b.w), 0.f);
        }
    } else {
#pragma unroll
        for (int i = 0; i < 16; i++) h[i] = 0.f;
    }

    if (WRITE_H) {
        if (g < n) {
            uint4 o;
            o.x = f32x4_to_fp8(h[0],  h[1],  h[2],  h[3]);
            o.y = f32x4_to_fp8(h[4],  h[5],  h[6],  h[7]);
            o.z = f32x4_to_fp8(h[8],  h[9],  h[10], h[11]);
            o.w = f32x4_to_fp8(h[12], h[13], h[14], h[15]);
            H4[(size_t)g * 8 + l8] = o;
        }
    } else {
#pragma unroll
        for (int i = 0; i < 16; i++) {
            h[i] += __shfl_xor(h[i], 8);
            h[i] += __shfl_xor(h[i], 16);
            h[i] += __shfl_xor(h[i], 32);
        }
        __shared__ float red[4 * 128];
        int w = threadIdx.x >> 6;
        int lane = threadIdx.x & 63;
        if (lane < 8) {
#pragma unroll
            for (int i = 0; i < 16; i++) red[w * 128 + lane * 16 + i] = h[i];
        }
        __syncthreads();
        if (threadIdx.x < 128) {
            float ssum = red[threadIdx.x] + red[128 + threadIdx.x] +
                         red[256 + threadIdx.x] + red[384 + threadIdx.x];
            atomicAdd(&gaccP[(blockIdx.x & 31) * 128 + threadIdx.x], ssum);
        }
    }
}

// ---------------- Final: reduce 32 pool stripes; out[a] = sum_k mean_k * Wl[k][a] + bl[a] ----

__global__ void final_k(const float* __restrict__ gaccP, const float* __restrict__ Wl,
                        const float* __restrict__ bl, float* __restrict__ out, float invN) {
    __shared__ float gs[128];
    int t = threadIdx.x;
    if (t < 128) {
        float s = 0.f;
#pragma unroll
        for (int c = 0; c < 32; c++) s += gaccP[c * 128 + t];
        gs[t] = s * invN;
    }
    __syncthreads();
    if (t < 16) {
        float s = bl[t];
        for (int k = 0; k < 128; k++) s = fmaf(gs[k], Wl[k * 16 + t], s);
        out[t] = s;
    }
}

extern "C" void kernel_launch(void* const* d_in, const int* in_sizes, int n_in,
                              void* d_out, int out_size, void* d_ws, size_t ws_size,
                              hipStream_t stream) {
    const float* x  = (const float*)d_in[0];
    const int*   ei = (const int*)d_in[1];
    const float* W1 = (const float*)d_in[2];
    const float* b1 = (const float*)d_in[3];
    const float* W2 = (const float*)d_in[4];
    const float* b2 = (const float*)d_in[5];
    const float* Wl = (const float*)d_in[6];
    const float* bl = (const float*)d_in[7];

    int N = in_sizes[0] / F;
    int E = in_sizes[1] / 2;
    const int* row = ei;
    const int* col = ei + E;

    char* ws = (char*)d_ws;
    size_t off = 0;
    auto alloc = [&](size_t bytes) -> void* {
        void* p = ws + off;
        off = (off + bytes + 255) & ~(size_t)255;
        return p;
    };
    int*          cnt    = (int*)          alloc((size_t)N * 4);
    int*          offs   = (int*)          alloc((size_t)(N + 1) * 4);
    int*          cursor = (int*)          alloc((size_t)N * 4);
    float*        dinv   = (float*)        alloc((size_t)N * 4);
    int*          bsum   = (int*)          alloc(1024 * 4);
    int*          srcb   = (int*)          alloc((size_t)E * 4);
    unsigned int* ybf8   = (unsigned int*) alloc((size_t)N * F);
    unsigned int* hbf8   = (unsigned int*) alloc((size_t)N * F);
    float*        gaccP  = (float*)        alloc(32 * 128 * 4);
    unsigned int* wf1g   = (unsigned int*) alloc(2048 * 16);
    unsigned int* wf2g   = (unsigned int*) alloc(2048 * 16);

    hipMemsetAsync(cnt, 0, (size_t)N * 4, stream);
    hipMemsetAsync(gaccP, 0, 32 * 128 * 4, stream);

    int bsize = (N + NBUCK - 1) / NBUCK;
    unsigned magic = (unsigned)((0x100000000ull + bsize - 1) / (unsigned long long)bsize);

    int NB = (N + 1023) / 1024;
    wprep2_k<<<16, 256, 0, stream>>>(W1, W2, wf1g, wf2g);
    count3_k<<<2048, 256, 0, stream>>>(col, cnt, E, magic);
    scan1_k<<<NB, 1024, 0, stream>>>(cnt, offs, dinv, bsum, N);
    scan3_k<<<(N + 1024) / 1024, 1024, 0, stream>>>(offs, cursor, bsum, NB, N, E);
    fill3_k<<<2048, 256, 0, stream>>>(row, col, cursor, srcb, E, magic);

    int GEMM_BLOCKS = (N + 127) / 128;
    int AGG_BLOCKS = (N + 31) / 32;

    gemm_mfma_k<0><<<GEMM_BLOCKS, 256, 0, stream>>>(x, wf1g, dinv, ybf8, N);
    agg_k<1><<<AGG_BLOCKS, 256, 0, stream>>>((const uint4*)ybf8, dinv, offs, srcb, b1,
                                             (uint4*)hbf8, nullptr, N);
    gemm_mfma_k<1><<<GEMM_BLOCKS, 256, 0, stream>>>(hbf8, wf2g, dinv, ybf8, N);
    agg_k<0><<<AGG_BLOCKS, 256, 0, stream>>>((const uint4*)ybf8, dinv, offs, srcb, b2,
                                             nullptr, gaccP, N);
    final_k<<<1, 128, 0, stream>>>(gaccP, Wl, bl, (float*)d_out, 1.0f / (float)N);
}

// Round 16
// 265.872 us; speedup vs baseline: 9.3083x; 1.0005x over previous
//
#include <hip/hip_runtime.h>
#include <hip/hip_bf16.h>

#define F 128
#define NBUCK 8

typedef float floatx2 __attribute__((ext_vector_type(2)));
typedef float f32x4 __attribute__((ext_vector_type(4)));
typedef short short8 __attribute__((ext_vector_type(8)));
typedef int intx4 __attribute__((ext_vector_type(4)));

static __device__ __forceinline__ unsigned short f2bf(float f) {
    unsigned int u = __float_as_uint(f);
    unsigned int r = (u + 0x7fffu + ((u >> 16) & 1u)) >> 16;   // RTN-even
    return (unsigned short)r;
}

static __device__ __forceinline__ float4 fp8x4_to_f32(unsigned int w) {
    floatx2 lo = __builtin_amdgcn_cvt_pk_f32_fp8((int)w, false);
    floatx2 hi = __builtin_amdgcn_cvt_pk_f32_fp8((int)w, true);
    return make_float4(lo[0], lo[1], hi[0], hi[1]);
}

static __device__ __forceinline__ unsigned int f32x4_to_fp8(float a, float b, float c, float d) {
    int w = 0;
    w = __builtin_amdgcn_cvt_pk_fp8_f32(a, b, w, false);
    w = __builtin_amdgcn_cvt_pk_fp8_f32(c, d, w, true);
    return (unsigned int)w;
}

// decode 16 fp8 (uint4) and masked-accumulate into a[16]
static __device__ __forceinline__ void acc16(float* a, uint4 w, float m) {
    float4 t;
    t = fp8x4_to_f32(w.x);
    a[0]  = fmaf(m, t.x, a[0]);  a[1]  = fmaf(m, t.y, a[1]);
    a[2]  = fmaf(m, t.z, a[2]);  a[3]  = fmaf(m, t.w, a[3]);
    t = fp8x4_to_f32(w.y);
    a[4]  = fmaf(m, t.x, a[4]);  a[5]  = fmaf(m, t.y, a[5]);
    a[6]  = fmaf(m, t.z, a[6]);  a[7]  = fmaf(m, t.w, a[7]);
    t = fp8x4_to_f32(w.z);
    a[8]  = fmaf(m, t.x, a[8]);  a[9]  = fmaf(m, t.y, a[9]);
    a[10] = fmaf(m, t.z, a[10]); a[11] = fmaf(m, t.w, a[11]);
    t = fp8x4_to_f32(w.w);
    a[12] = fmaf(m, t.x, a[12]); a[13] = fmaf(m, t.y, a[13]);
    a[14] = fmaf(m, t.z, a[14]); a[15] = fmaf(m, t.w, a[15]);
}

// ---------------- CSR build: XCD-local via full-stream read + range mask ----------------
// bucket b = blockIdx&7 -> XCD under round-robin dispatch. Blocks stream the whole edge
// list but touch only their node range. Stream loads are NON-TEMPORAL so they don't
// evict the dirty src window / cnt / cursor slices from the XCD's L2 (R14: without nt,
// src writeback amplification was 12x -> 74.6 MB WRITE_SIZE).

__global__ __launch_bounds__(256) void count3_k(const int* __restrict__ col,
                                                int* __restrict__ cnt,
                                                int E, unsigned magic) {
    int b = blockIdx.x & 7;
    int bi = blockIdx.x >> 3;
    int nb = gridDim.x >> 3;
    int stride = nb * 1024;
    for (int e0 = (bi * 256 + threadIdx.x) * 4; e0 < E; e0 += stride) {
        if (e0 + 4 <= E) {
            intx4 c4 = __builtin_nontemporal_load((const intx4*)&col[e0]);
            int b0 = min(7, (int)__umulhi((unsigned)c4[0], magic));
            int b1 = min(7, (int)__umulhi((unsigned)c4[1], magic));
            int b2 = min(7, (int)__umulhi((unsigned)c4[2], magic));
            int b3 = min(7, (int)__umulhi((unsigned)c4[3], magic));
            if (b0 == b) atomicAdd(&cnt[c4[0]], 1);
            if (b1 == b) atomicAdd(&cnt[c4[1]], 1);
            if (b2 == b) atomicAdd(&cnt[c4[2]], 1);
            if (b3 == b) atomicAdd(&cnt[c4[3]], 1);
        } else {
            for (int e = e0; e < E; e++) {
                int c = col[e];
                if (min(7, (int)__umulhi((unsigned)c, magic)) == b)
                    atomicAdd(&cnt[c], 1);
            }
        }
    }
}

__global__ __launch_bounds__(256) void fill3_k(const int* __restrict__ row,
                                               const int* __restrict__ col,
                                               int* __restrict__ cursor,
                                               int* __restrict__ src,
                                               int E, unsigned magic) {
    int b = blockIdx.x & 7;
    int bi = blockIdx.x >> 3;
    int nb = gridDim.x >> 3;
    int stride = nb * 1024;
    for (int e0 = (bi * 256 + threadIdx.x) * 4; e0 < E; e0 += stride) {
        if (e0 + 4 <= E) {
            intx4 c4 = __builtin_nontemporal_load((const intx4*)&col[e0]);
            intx4 r4 = __builtin_nontemporal_load((const intx4*)&row[e0]);
            int b0 = min(7, (int)__umulhi((unsigned)c4[0], magic));
            int b1 = min(7, (int)__umulhi((unsigned)c4[1], magic));
            int b2 = min(7, (int)__umulhi((unsigned)c4[2], magic));
            int b3 = min(7, (int)__umulhi((unsigned)c4[3], magic));
            if (b0 == b) src[atomicAdd(&cursor[c4[0]], 1)] = r4[0];
            if (b1 == b) src[atomicAdd(&cursor[c4[1]], 1)] = r4[1];
            if (b2 == b) src[atomicAdd(&cursor[c4[2]], 1)] = r4[2];
            if (b3 == b) src[atomicAdd(&cursor[c4[3]], 1)] = r4[3];
        } else {
            for (int e = e0; e < E; e++) {
                int c = col[e];
                if (min(7, (int)__umulhi((unsigned)c, magic)) == b)
                    src[atomicAdd(&cursor[c], 1)] = row[e];
            }
        }
    }
}

// ---------------- scans (scan2 fused into scan3) ----------------

__global__ void scan1_k(const int* __restrict__ cnt, int* __restrict__ offs,
                        float* __restrict__ dinv, int* __restrict__ bsum, int n) {
    __shared__ int s[1024];
    int tid = threadIdx.x;
    int i = blockIdx.x * 1024 + tid;
    int v = (i < n) ? cnt[i] : 0;
    s[tid] = v;
    __syncthreads();
    for (int off = 1; off < 1024; off <<= 1) {
        int t = (tid >= off) ? s[tid - off] : 0;
        __syncthreads();
        s[tid] += t;
        __syncthreads();
    }
    if (i < n) {
        offs[i] = s[tid] - v;
        dinv[i] = rsqrtf((float)(v + 1));
    }
    if (tid == 1023) bsum[blockIdx.x] = s[1023];
}

// offs[i] += prefix(bsum[0..block)); writes cursor copy; handles i==n. NB <= 128.
__global__ void scan3_k(int* __restrict__ offs, int* __restrict__ cursor,
                        const int* __restrict__ bsum, int nbsum, int n, int E) {
    __shared__ int sred[128];
    int tid = threadIdx.x;
    if (tid < 128)
        sred[tid] = (tid < nbsum && tid < blockIdx.x) ? bsum[tid] : 0;
    __syncthreads();
    for (int s = 64; s > 0; s >>= 1) {
        if (tid < s) sred[tid] += sred[tid + s];
        __syncthreads();
    }
    int base = sred[0];
    int i = blockIdx.x * 1024 + tid;
    if (i < n) {
        int o = offs[i] + base;
        offs[i] = o;
        cursor[i] = o;
    }
    if (i == n) offs[n] = E;
}

// ---------------- W fragment prep (both weights, one launch) ----------------
// slot = (ct*4+ks)*64 + lane; 8 bf16: W[ks*32+(lane>>4)*8+j][ct*16+(lane&15)]

__global__ void wprep2_k(const float* __restrict__ W1, const float* __restrict__ W2,
                         unsigned int* __restrict__ wf1, unsigned int* __restrict__ wf2) {
    int half = blockIdx.x >> 3;
    const float* W = half ? W2 : W1;
    unsigned int* wfg = half ? wf2 : wf1;
    int slot = (blockIdx.x & 7) * 256 + threadIdx.x;   // 0..2047
    int l = slot & 63;
    int ks = (slot >> 6) & 3;
    int ct = slot >> 8;
    int n0 = ct * 16 + (l & 15);
    int k0 = ks * 32 + (l >> 4) * 8;
    unsigned short t[8];
#pragma unroll
    for (int j = 0; j < 8; j++) t[j] = f2bf(W[(k0 + j) * F + n0]);
    uint4 v;
    v.x = (unsigned)t[0] | ((unsigned)t[1] << 16);
    v.y = (unsigned)t[2] | ((unsigned)t[3] << 16);
    v.z = (unsigned)t[4] | ((unsigned)t[5] << 16);
    v.w = (unsigned)t[6] | ((unsigned)t[7] << 16);
    ((uint4*)wfg)[slot] = v;
}

// ---------------- MFMA GEMM: Y8[r][128] = fp8( dinv[r] * (X[r,:] @ W) ) ----------------

template <int FP8IN>
__global__ __launch_bounds__(256) void gemm_mfma_k(const void* __restrict__ Xin,
                                                   const unsigned int* __restrict__ wfg,
                                                   const float* __restrict__ dinv,
                                                   unsigned int* __restrict__ Y8, int n) {
    __shared__ unsigned short wf[16384];     // 32 KB fragment-ordered W
    __shared__ float Dt[4][16 * 132];        // per-wave D tile, padded
    for (int i = threadIdx.x; i < 2048; i += 256)
        ((uint4*)wf)[i] = ((const uint4*)wfg)[i];
    __syncthreads();

    int l = threadIdx.x & 63;
    int w = threadIdx.x >> 6;
    const float* Xf = (const float*)Xin;
    const uint2* X8 = (const uint2*)Xin;

    for (int t = 0; t < 2; t++) {
        int rbase = blockIdx.x * 128 + w * 32 + t * 16;
        int arow = rbase + (l & 15);
        if (arow > n - 1) arow = n - 1;

        short8 af[4];
#pragma unroll
        for (int ks = 0; ks < 4; ks++) {
            short8 f;
            if (FP8IN) {
                uint2 v = X8[(size_t)arow * 16 + ks * 4 + (l >> 4)];
                float4 lo = fp8x4_to_f32(v.x);
                float4 hi = fp8x4_to_f32(v.y);
                f[0] = (short)f2bf(lo.x); f[1] = (short)f2bf(lo.y);
                f[2] = (short)f2bf(lo.z); f[3] = (short)f2bf(lo.w);
                f[4] = (short)f2bf(hi.x); f[5] = (short)f2bf(hi.y);
                f[6] = (short)f2bf(hi.z); f[7] = (short)f2bf(hi.w);
            } else {
                const float* xr = Xf + (size_t)arow * F + ks * 32 + (l >> 4) * 8;
                float4 a0 = *(const float4*)xr;
                float4 a1 = *(const float4*)(xr + 4);
                f[0] = (short)f2bf(a0.x); f[1] = (short)f2bf(a0.y);
                f[2] = (short)f2bf(a0.z); f[3] = (short)f2bf(a0.w);
                f[4] = (short)f2bf(a1.x); f[5] = (short)f2bf(a1.y);
                f[6] = (short)f2bf(a1.z); f[7] = (short)f2bf(a1.w);
            }
            af[ks] = f;
        }

        f32x4 acc[8];
#pragma unroll
        for (int ct = 0; ct < 8; ct++) acc[ct] = (f32x4){0.f, 0.f, 0.f, 0.f};

#pragma unroll
        for (int ct = 0; ct < 8; ct++) {
#pragma unroll
            for (int ks = 0; ks < 4; ks++) {
                short8 bf = *(const short8*)&wf[((((ct << 2) | ks) << 6) + l) * 8];
                acc[ct] = __builtin_amdgcn_mfma_f32_16x16x32_bf16(af[ks], bf, acc[ct], 0, 0, 0);
            }
        }

        float* dt = Dt[w];
#pragma unroll
        for (int ct = 0; ct < 8; ct++)
#pragma unroll
            for (int r = 0; r < 4; r++)
                dt[((l >> 4) * 4 + r) * 132 + ct * 16 + (l & 15)] = acc[ct][r];
        __syncthreads();

#pragma unroll
        for (int i = 0; i < 8; i++) {
            int wordid = l + i * 64;
            int rrow = wordid >> 5;
            int wc = wordid & 31;
            int grow = rbase + rrow;
            if (grow < n) {
                float sc = dinv[grow];
                const float* p = &dt[rrow * 132 + wc * 4];
                unsigned int pk = f32x4_to_fp8(sc * p[0], sc * p[1], sc * p[2], sc * p[3]);
                __builtin_nontemporal_store(pk, &Y8[(size_t)grow * 32 + wc]);
            }
        }
        __syncthreads();
    }
}

// ---------------- Aggregation: 8-lane group per node, 8-deep pipelined gathers ----------------

template <int WRITE_H>
__global__ __launch_bounds__(256) void agg_k(const uint4* __restrict__ Y4,
                                             const float* __restrict__ dinv,
                                             const int* __restrict__ offs,
                                             const int* __restrict__ src,
                                             const float* __restrict__ bias,
                                             uint4* __restrict__ H4,
                                             float* __restrict__ gaccP, int n) {
    int l8 = threadIdx.x & 7;          // lane in group: 16 feats
    int grp = threadIdx.x >> 3;        // 0..31: node slot
    int g = blockIdx.x * 32 + grp;

    float a[16];
#pragma unroll
    for (int i = 0; i < 16; i++) a[i] = 0.f;
    float dv = 0.f;

    if (g < n) {
        uint4 selfw = Y4[(size_t)g * 8 + l8];   // issue early
        int s = offs[g], e = offs[g + 1];
        dv = dinv[g];
        acc16(a, selfw, 1.f);

        if (s < e) {
            int em1 = e - 1;
            int u[8], nu[8];
#pragma unroll
            for (int i = 0; i < 8; i++) u[i] = src[min(s + i, em1)];

            for (int base = s; base < e; base += 8) {
                uint4 wv[8];
#pragma unroll
                for (int i = 0; i < 8; i++) wv[i] = Y4[(size_t)u[i] * 8 + l8];
                int nb = base + 8;
                if (nb < e) {
#pragma unroll
                    for (int i = 0; i < 8; i++) nu[i] = src[min(nb + i, em1)];
                }
                acc16(a, wv[0], 1.f);
#pragma unroll
                for (int i = 1; i < 8; i++) {
                    float m = (base + i <= em1) ? 1.f : 0.f;
                    acc16(a, wv[i], m);
                }
#pragma unroll
                for (int i = 0; i < 8; i++) u[i] = nu[i];
            }
        }
    }

    float h[16];
    if (g < n) {
        const float4* b4 = (const float4*)bias;
#pragma unroll
        for (int j = 0; j < 4; j++) {
            float4 b = b4[l8 * 4 + j];
            h[j * 4 + 0] = fmaxf(fmaf(dv, a[j * 4 + 0], b.x), 0.f);
            h[j * 4 + 1] = fmaxf(fmaf(dv, a[j * 4 + 1], b.y), 0.f);
            h[j * 4 + 2] = fmaxf(fmaf(dv, a[j * 4 + 2], b.z), 0.f);
            h[j * 4 + 3] = fmaxf(fmaf(dv, a[j * 4 + 3], b.w), 0.f);
        }
    } else {
#pragma unroll
        for (int i = 0; i < 16; i++) h[i] = 0.f;
    }

    if (WRITE_H) {
        if (g < n) {
            uint4 o;
            o.x = f32x4_to_fp8(h[0],  h[1],  h[2],  h[3]);
            o.y = f32x4_to_fp8(h[4],  h[5],  h[6],  h[7]);
            o.z = f32x4_to_fp8(h[8],  h[9],  h[10], h[11]);
            o.w = f32x4_to_fp8(h[12], h[13], h[14], h[15]);
            H4[(size_t)g * 8 + l8] = o;
        }
    } else {
#pragma unroll
        for (int i = 0; i < 16; i++) {
            h[i] += __shfl_xor(h[i], 8);
            h[i] += __shfl_xor(h[i], 16);
            h[i] += __shfl_xor(h[i], 32);
        }
        __shared__ float red[4 * 128];
        int w = threadIdx.x >> 6;
        int lane = threadIdx.x & 63;
        if (lane < 8) {
#pragma unroll
            for (int i = 0; i < 16; i++) red[w * 128 + lane * 16 + i] = h[i];
        }
        __syncthreads();
        if (threadIdx.x < 128) {
            float ssum = red[threadIdx.x] + red[128 + threadIdx.x] +
                         red[256 + threadIdx.x] + red[384 + threadIdx.x];
            atomicAdd(&gaccP[(blockIdx.x & 31) * 128 + threadIdx.x], ssum);
        }
    }
}

// ---------------- Final: reduce 32 pool stripes; out[a] = sum_k mean_k * Wl[k][a] + bl[a] ----

__global__ void final_k(const float* __restrict__ gaccP, const float* __restrict__ Wl,
                        const float* __restrict__ bl, float* __restrict__ out, float invN) {
    __shared__ float gs[128];
    int t = threadIdx.x;
    if (t < 128) {
        float s = 0.f;
#pragma unroll
        for (int c = 0; c < 32; c++) s += gaccP[c * 128 + t];
        gs[t] = s * invN;
    }
    __syncthreads();
    if (t < 16) {
        float s = bl[t];
        for (int k = 0; k < 128; k++) s = fmaf(gs[k], Wl[k * 16 + t], s);
        out[t] = s;
    }
}

extern "C" void kernel_launch(void* const* d_in, const int* in_sizes, int n_in,
                              void* d_out, int out_size, void* d_ws, size_t ws_size,
                              hipStream_t stream) {
    const float* x  = (const float*)d_in[0];
    const int*   ei = (const int*)d_in[1];
    const float* W1 = (const float*)d_in[2];
    const float* b1 = (const float*)d_in[3];
    const float* W2 = (const float*)d_in[4];
    const float* b2 = (const float*)d_in[5];
    const float* Wl = (const float*)d_in[6];
    const float* bl = (const float*)d_in[7];

    int N = in_sizes[0] / F;
    int E = in_sizes[1] / 2;
    const int* row = ei;
    const int* col = ei + E;

    char* ws = (char*)d_ws;
    size_t off = 0;
    auto alloc = [&](size_t bytes) -> void* {
        void* p = ws + off;
        off = (off + bytes + 255) & ~(size_t)255;
        return p;
    };
    int*          cnt    = (int*)          alloc((size_t)N * 4);
    int*          offs   = (int*)          alloc((size_t)(N + 1) * 4);
    int*          cursor = (int*)          alloc((size_t)N * 4);
    float*        dinv   = (float*)        alloc((size_t)N * 4);
    int*          bsum   = (int*)          alloc(1024 * 4);
    int*          srcb   = (int*)          alloc((size_t)E * 4);
    unsigned int* ybf8   = (unsigned int*) alloc((size_t)N * F);
    unsigned int* hbf8   = (unsigned int*) alloc((size_t)N * F);
    float*        gaccP  = (float*)        alloc(32 * 128 * 4);
    unsigned int* wf1g   = (unsigned int*) alloc(2048 * 16);
    unsigned int* wf2g   = (unsigned int*) alloc(2048 * 16);

    hipMemsetAsync(cnt, 0, (size_t)N * 4, stream);
    hipMemsetAsync(gaccP, 0, 32 * 128 * 4, stream);

    int bsize = (N + NBUCK - 1) / NBUCK;
    unsigned magic = (unsigned)((0x100000000ull + bsize - 1) / (unsigned long long)bsize);

    int NB = (N + 1023) / 1024;
    wprep2_k<<<16, 256, 0, stream>>>(W1, W2, wf1g, wf2g);
    count3_k<<<2048, 256, 0, stream>>>(col, cnt, E, magic);
    scan1_k<<<NB, 1024, 0, stream>>>(cnt, offs, dinv, bsum, N);
    scan3_k<<<(N + 1024) / 1024, 1024, 0, stream>>>(offs, cursor, bsum, NB, N, E);
    fill3_k<<<2048, 256, 0, stream>>>(row, col, cursor, srcb, E, magic);

    int GEMM_BLOCKS = (N + 127) / 128;
    int AGG_BLOCKS = (N + 31) / 32;

    gemm_mfma_k<0><<<GEMM_BLOCKS, 256, 0, stream>>>(x, wf1g, dinv, ybf8, N);
    agg_k<1><<<AGG_BLOCKS, 256, 0, stream>>>((const uint4*)ybf8, dinv, offs, srcb, b1,
                                             (uint4*)hbf8, nullptr, N);
    gemm_mfma_k<1><<<GEMM_BLOCKS, 256, 0, stream>>>(hbf8, wf2g, dinv, ybf8, N);
    agg_k<0><<<AGG_BLOCKS, 256, 0, stream>>>((const uint4*)ybf8, dinv, offs, srcb, b2,
                                             nullptr, gaccP, N);
    final_k<<<1, 128, 0, stream>>>(gaccP, Wl, bl, (float*)d_out, 1.0f / (float)N);
}